// Round 1
// 374.102 us; speedup vs baseline: 1.1771x; 1.1771x over previous
//
#include <hip/hip_runtime.h>

typedef __bf16 bf16;
typedef __bf16 bf16x8 __attribute__((ext_vector_type(8)));
typedef __bf16 bf16x4 __attribute__((ext_vector_type(4)));
typedef float f32x4 __attribute__((ext_vector_type(4)));

#define MFMA16(a, b, c) __builtin_amdgcn_mfma_f32_16x16x32_bf16(a, b, c, 0, 0, 0)

// Problem constants
#define Bq 2
#define Sq 2048
#define Eq 2048
#define Hq 16
#define Dq 128
#define N3E 6144

#define GLOAD_LDS16(gp, lp) \
  __builtin_amdgcn_global_load_lds( \
      (const __attribute__((address_space(1))) void*)(gp), \
      (__attribute__((address_space(3))) void*)(lp), 16, 0, 0)

__device__ __forceinline__ bf16 f2bf(float f) {
  unsigned u = __builtin_bit_cast(unsigned, f);
  u += 0x7FFFu + ((u >> 16) & 1u);
  unsigned short h = (unsigned short)(u >> 16);
  return __builtin_bit_cast(bf16, h);
}
__device__ __forceinline__ float bf2f(bf16 b) {
  unsigned short h = __builtin_bit_cast(unsigned short, b);
  return __builtin_bit_cast(float, (unsigned)h << 16);
}

// ---------------------------------------------------------------------------
// Kernel 0a: x fp32 -> xb bf16 (elementwise, 8 elems/thread)
// ---------------------------------------------------------------------------
__global__ __launch_bounds__(256) void convert_x(const float* __restrict__ x,
                                                 bf16* __restrict__ xb) {
  const size_t i = ((size_t)blockIdx.x * 256 + threadIdx.x) * 8;
  float4 a = *(const float4*)(x + i);
  float4 b = *(const float4*)(x + i + 4);
  bf16x8 o;
  o[0] = f2bf(a.x); o[1] = f2bf(a.y); o[2] = f2bf(a.z); o[3] = f2bf(a.w);
  o[4] = f2bf(b.x); o[5] = f2bf(b.y); o[6] = f2bf(b.z); o[7] = f2bf(b.w);
  *(bf16x8*)(xb + i) = o;
}

// ---------------------------------------------------------------------------
// Kernel 0b: W fp32 [k][n] -> wt bf16 [n][k] (64x64 LDS tile transpose)
// ---------------------------------------------------------------------------
__global__ __launch_bounds__(256) void convert_wt(const float* __restrict__ w,
                                                  bf16* __restrict__ wt) {
  __shared__ __align__(16) bf16 T[64][72];
  const int tid = threadIdx.x;
  const int kb = blockIdx.x & 31;  // 2048/64
  const int nb = blockIdx.x >> 5;  // 6144/64
  const int k0 = kb * 64, n0 = nb * 64;
  {
    const int kr = tid >> 4, nc = (tid & 15) * 4;
#pragma unroll
    for (int p = 0; p < 4; ++p) {
      const int k = kr + p * 16;
      float4 v = *(const float4*)(w + (size_t)(k0 + k) * N3E + n0 + nc);
      T[nc + 0][k] = f2bf(v.x);
      T[nc + 1][k] = f2bf(v.y);
      T[nc + 2][k] = f2bf(v.z);
      T[nc + 3][k] = f2bf(v.w);
    }
  }
  __syncthreads();
#pragma unroll
  for (int q = 0; q < 2; ++q) {
    const int id = q * 256 + tid;
    const int n = id >> 3, ch = id & 7;
    bf16x8 v = *(const bf16x8*)&T[n][ch * 8];
    *(bf16x8*)(wt + (size_t)(n0 + n) * Eq + k0 + ch * 8) = v;
  }
}

// ---------------------------------------------------------------------------
// Kernel 0c: RoPE cos/sin table [Sq][Dq/2] of float2 (1 MB). Removes
// per-element __sincosf/__expf from the GEMM epilogue (VALU-bound otherwise).
// ---------------------------------------------------------------------------
__global__ __launch_bounds__(256) void rope_table(float2* __restrict__ tbl) {
  const int i = blockIdx.x * 256 + threadIdx.x;  // 0 .. Sq*64-1
  const int s = i >> 6, d = i & 63;
  const float freq = __expf(-(float)d * 0.14391157f);  // ln(10000)/64
  const float ang = (float)s * freq;
  float sv, cv;
  __sincosf(ang, &sv, &cv);
  tbl[i] = make_float2(cv, sv);
}

// ---------------------------------------------------------------------------
// Kernel 1: qkv = xb @ wt^T. NEW: 128(M)x256(N) tile, BK=64, ring-3 LDS
// (144 KiB), 512 threads = 8 waves (2M x 4N, 64x64 per wave).
// Deep pipeline per T3+T4: stage tile t+2 while computing tile t; the
// inter-tile wait is a COUNTED s_waitcnt vmcnt(6) + raw s_barrier (no
// compiler vmcnt(0) drain). Ring-3 makes the counted wait clobber-free by
// construction. LDS layout row-major [rows][64] with XOR column-swizzle
// (kch ^= row&7) applied on the GLOBAL source address (rule 21), giving
// both coalesced 128B global rows and floor-level LDS bank spread.
// Grid 768 = 3*256 (perfect CU quantization) with XCD-aware swizzle.
// Epilogue: per-head LDS transpose + table-driven RoPE (q/k) / transpose
// store (v).
// ---------------------------------------------------------------------------
__global__ __launch_bounds__(512, 2) void gemm_qkv(
    const bf16* __restrict__ xb, const bf16* __restrict__ wt,
    const float2* __restrict__ tbl, bf16* __restrict__ qws,
    bf16* __restrict__ kws, bf16* __restrict__ vtws) {
  // 3 slots x (A 128x64 + B 256x64) bf16 = 3 * 24576 elems = 144 KiB
  __shared__ __align__(16) bf16 LDS[3 * 24576];

  const int tid = threadIdx.x;
  const int lane = tid & 63, wv = tid >> 6;
  const int q4 = lane >> 4, c = lane & 15;
  const int wm = (wv >> 2) * 64;   // wave M offset: 0 / 64
  const int wn = (wv & 3) * 64;    // wave N offset: 0 / 64 / 128 / 192

  // XCD swizzle: 768 blocks % 8 == 0 -> 96 consecutive wg per XCD.
  // n varies fastest within an XCD chunk -> per-XCD A panel (2 MB) L2-hits.
  const int bid = blockIdx.x;
  const int wg = (bid & 7) * 96 + (bid >> 3);
  const int m0 = (wg / 24) * 128;
  const int n0 = (wg % 24) * 256;

  f32x4 acc[4][4];
#pragma unroll
  for (int i = 0; i < 4; ++i)
#pragma unroll
    for (int j = 0; j < 4; ++j) acc[i][j] = {0.f, 0.f, 0.f, 0.f};

  const int NT = Eq / 64;  // 32 K-tiles

  auto stage = [&](int t, int st) {
    bf16* ab = LDS + st * 24576;
    bf16* bb = ab + 8192;
    const int k0 = t * 64;
    // A: 128 rows x 64 cols = 2 gloads; lanes 8-per-row -> 128B coalesced.
#pragma unroll
    for (int it = 0; it < 2; ++it) {
      const int slot = it * 512 + tid;
      const int row = slot >> 3, kch = slot & 7;
      const int kcs = kch ^ (row & 7);  // source pre-swizzle (involution)
      GLOAD_LDS16(xb + (size_t)(m0 + row) * Eq + k0 + kcs * 8, ab + slot * 8);
    }
    // B: 256 rows x 64 cols = 4 gloads.
#pragma unroll
    for (int it = 0; it < 4; ++it) {
      const int slot = it * 512 + tid;
      const int row = slot >> 3, kch = slot & 7;
      const int kcs = kch ^ (row & 7);
      GLOAD_LDS16(wt + (size_t)(n0 + row) * Eq + k0 + kcs * 8, bb + slot * 8);
    }
  };

  // Prologue: tiles 0,1 in flight; wait only for tile 0 (6 newest = tile 1).
  stage(0, 0);
  stage(1, 1);
  asm volatile("s_waitcnt vmcnt(6)" ::: "memory");
  __builtin_amdgcn_s_barrier();

  int stC = 0;
#pragma unroll 1
  for (int t = 0; t < NT; ++t) {
    if (t + 2 < NT) {
      int ss = stC + 2;
      if (ss >= 3) ss -= 3;
      stage(t + 2, ss);  // slot (t+2)%3: not read by tiles t, t+1
    }
    const bf16* A = LDS + stC * 24576;
    const bf16* Bb = A + 8192;
#pragma unroll
    for (int kk = 0; kk < 64; kk += 32) {
      const int bch = kk >> 3;  // 0 or 4
      bf16x8 af[4], bfr[4];
#pragma unroll
      for (int i = 0; i < 4; ++i)
        af[i] = *(const bf16x8*)
            &A[(wm + i * 16 + c) * 64 + ((bch + q4) ^ (c & 7)) * 8];
#pragma unroll
      for (int j = 0; j < 4; ++j)
        bfr[j] = *(const bf16x8*)
            &Bb[(wn + j * 16 + c) * 64 + ((bch + q4) ^ (c & 7)) * 8];
      __builtin_amdgcn_s_setprio(1);
#pragma unroll
      for (int i = 0; i < 4; ++i)
#pragma unroll
        for (int j = 0; j < 4; ++j)
          acc[i][j] = MFMA16(af[i], bfr[j], acc[i][j]);
      __builtin_amdgcn_s_setprio(0);
    }
    if (t + 1 < NT) {
      // Counted wait: drains loads(t+1) (older), keeps loads(t+2) in flight.
      if (t + 2 < NT) asm volatile("s_waitcnt vmcnt(6)" ::: "memory");
      else            asm volatile("s_waitcnt vmcnt(0)" ::: "memory");
      __builtin_amdgcn_s_barrier();
    }
    stC = stC == 2 ? 0 : stC + 1;
  }
  __syncthreads();  // full drain once; LDS reused below

  // ---- epilogue: per-head (2 heads per 256-wide N tile) ----
  const int t3 = n0 >> 11;         // 0=q, 1=k, 2=v
  const int b = m0 >> 11;
  const int s0 = m0 & 2047;
  const int h0 = (n0 & 2047) >> 7;

  bf16* E = LDS;  // reused: [128][136] bf16 = 34816 B

  if (t3 == 2) {
#pragma unroll 1
    for (int hh = 0; hh < 2; ++hh) {
      if (((wv & 3) >> 1) == hh) {  // waves owning this head's 128 cols
#pragma unroll
        for (int i = 0; i < 4; ++i)
#pragma unroll
          for (int j = 0; j < 4; ++j) {
            bf16x4 pv;
            pv[0] = f2bf(acc[i][j][0]); pv[1] = f2bf(acc[i][j][1]);
            pv[2] = f2bf(acc[i][j][2]); pv[3] = f2bf(acc[i][j][3]);
            // transposed dump: E[d][s]
            *(bf16x4*)&E[((wn & 127) + j * 16 + c) * 136 + wm + i * 16 +
                         q4 * 4] = pv;
          }
      }
      __syncthreads();
      bf16* vbase = vtws + ((size_t)(b * Hq + h0 + hh) * Dq) * Sq + s0;
#pragma unroll
      for (int p = 0; p < 4; ++p) {
        const int id = p * 512 + tid;
        const int d = id >> 4, ch = id & 15;
        bf16x8 v = *(const bf16x8*)&E[d * 136 + ch * 8];
        *(bf16x8*)&vbase[(size_t)d * Sq + ch * 8] = v;
      }
      __syncthreads();
    }
  } else {
#pragma unroll 1
    for (int hh = 0; hh < 2; ++hh) {
      if (((wv & 3) >> 1) == hh) {
#pragma unroll
        for (int i = 0; i < 4; ++i)
#pragma unroll
          for (int j = 0; j < 4; ++j)
#pragma unroll
            for (int rr = 0; rr < 4; ++rr)
              E[(wm + i * 16 + q4 * 4 + rr) * 136 + (wn & 127) + j * 16 + c] =
                  f2bf(acc[i][j][rr]);
      }
      __syncthreads();
      bf16* hd = ((t3 == 0) ? qws : kws) +
                 ((size_t)(b * Hq + h0 + hh) * Sq + s0) * Dq;
#pragma unroll
      for (int p = 0; p < 2; ++p) {
        const int row = p * 64 + (tid >> 3);
        const int dlow = (tid & 7) * 8;
        const int s = s0 + row;
        bf16x8 lo = *(const bf16x8*)&E[row * 136 + dlow];
        bf16x8 hi = *(const bf16x8*)&E[row * 136 + 64 + dlow];
        const float2* tb = tbl + (size_t)s * 64 + dlow;
        bf16x8 olo, ohi;
#pragma unroll
        for (int e = 0; e < 8; ++e) {
          const float cv = tb[e].x, sv = tb[e].y;
          const float x1 = bf2f(lo[e]), x2 = bf2f(hi[e]);
          olo[e] = f2bf(x1 * cv - x2 * sv);
          ohi[e] = f2bf(x2 * cv + x1 * sv);
        }
        *(bf16x8*)&hd[(size_t)row * Dq + dlow] = olo;
        *(bf16x8*)&hd[(size_t)row * Dq + 64 + dlow] = ohi;
      }
      __syncthreads();
    }
  }
}

// ---------------------------------------------------------------------------
// Kernel 3: flash attention (R5 structure) + qt CU-pairing fix. Unchanged
// this round; its counters will surface in top-5 next round.
// ---------------------------------------------------------------------------
__global__ __launch_bounds__(256, 2) void attn_kernel(
    const bf16* __restrict__ qws, const bf16* __restrict__ kws,
    const bf16* __restrict__ vtws, float* __restrict__ out) {
  __shared__ __align__(16) bf16 Kld[2][8192];
  __shared__ __align__(16) bf16 Vld[2][8192];
  __shared__ __align__(16) bf16 Plds[4][16][72];

  const int tid = threadIdx.x, lane = tid & 63, wave = tid >> 6;
  const int q4 = lane >> 4, c = lane & 15;
  const int h = blockIdx.y, b = blockIdx.z;
  const int qt = b ? blockIdx.x : (15 - blockIdx.x);  // CU-pair balance
  const size_t bh = (size_t)(b * Hq + h);
  const bf16* qbase = qws + bh * Sq * Dq;
  const bf16* kbase = kws + bh * Sq * Dq;
  const bf16* vbase = vtws + bh * Dq * Sq;
  const int q0 = qt * 128 + wave * 32;
  const float kSc = 0.08838834764831845f * 1.4426950408889634f;

  bf16x8 qf[2][4];
#pragma unroll
  for (int g = 0; g < 2; ++g)
#pragma unroll
    for (int ks = 0; ks < 4; ++ks)
      qf[g][ks] = *(const bf16x8*)
          &qbase[(size_t)(q0 + g * 16 + c) * Dq + ks * 32 + q4 * 8];

  f32x4 Ot[2][8];
  float m_i[2], l_i[2];
#pragma unroll
  for (int g = 0; g < 2; ++g) {
#pragma unroll
    for (int dj = 0; dj < 8; ++dj) Ot[g][dj] = {0.f, 0.f, 0.f, 0.f};
    m_i[g] = -1e30f; l_i[g] = 0.f;
  }

  const int nchunks = 2 * qt + 2;

#pragma unroll
  for (int it = 0; it < 4; ++it) {
    const int slot = it * 256 + tid;
    GLOAD_LDS16(kbase + (size_t)(slot & 63) * Dq + (slot >> 6) * 8,
                &Kld[0][slot * 8]);
    GLOAD_LDS16(vbase + (size_t)(slot & 127) * Sq + (slot >> 7) * 8,
                &Vld[0][slot * 8]);
  }
  __syncthreads();

  for (int kb = 0; kb < nchunks; ++kb) {
    const int buf = kb & 1;
    if (kb + 1 < nchunks) {
      const int nb = buf ^ 1;
      const int koff = (kb + 1) * 64;
#pragma unroll
      for (int it = 0; it < 4; ++it) {
        const int slot = it * 256 + tid;
        GLOAD_LDS16(kbase + (size_t)(koff + (slot & 63)) * Dq + (slot >> 6) * 8,
                    &Kld[nb][slot * 8]);
        GLOAD_LDS16(vbase + (size_t)(slot & 127) * Sq + koff + (slot >> 7) * 8,
                    &Vld[nb][slot * 8]);
      }
    }
    const bool masked = (kb >= 2 * qt);
#pragma unroll
    for (int g = 0; g < 2; ++g) {
      const int qg = q0 + g * 16 + c;
      f32x4 st[4];
#pragma unroll
      for (int j8 = 0; j8 < 4; ++j8) st[j8] = {0.f, 0.f, 0.f, 0.f};
#pragma unroll
      for (int ks = 0; ks < 4; ++ks) {
        const bf16x8 qv = qf[g][ks];
#pragma unroll
        for (int j8 = 0; j8 < 4; ++j8) {
          const bf16x8 kv = *(const bf16x8*)
              &Kld[buf][((ks * 4 + q4) * 64 + j8 * 16 + c) * 8];
          st[j8] = MFMA16(kv, qv, st[j8]);
        }
      }
      if (masked) {
        const int kb64 = kb * 64 + q4 * 4;
#pragma unroll
        for (int j8 = 0; j8 < 4; ++j8)
#pragma unroll
          for (int rr = 0; rr < 4; ++rr)
            if (kb64 + j8 * 16 + rr > qg) st[j8][rr] = -1e30f;
      }
      float mloc = -1e30f;
#pragma unroll
      for (int j8 = 0; j8 < 4; ++j8)
#pragma unroll
        for (int rr = 0; rr < 4; ++rr) mloc = fmaxf(mloc, st[j8][rr]);
      mloc = fmaxf(mloc, __shfl_xor(mloc, 16, 64));
      mloc = fmaxf(mloc, __shfl_xor(mloc, 32, 64));
      const float mn = fmaxf(m_i[g], mloc);
      const float alpha = exp2f((m_i[g] - mn) * kSc);
      m_i[g] = mn;
      float ssum = 0.f;
#pragma unroll
      for (int j8 = 0; j8 < 4; ++j8)
#pragma unroll
        for (int rr = 0; rr < 4; ++rr) {
          const float p = exp2f((st[j8][rr] - mn) * kSc);
          st[j8][rr] = p;
          ssum += p;
        }
      ssum += __shfl_xor(ssum, 16, 64);
      ssum += __shfl_xor(ssum, 32, 64);
      l_i[g] = l_i[g] * alpha + ssum;
#pragma unroll
      for (int dj = 0; dj < 8; ++dj) Ot[g][dj] *= alpha;
#pragma unroll
      for (int j8 = 0; j8 < 4; ++j8) {
        bf16x4 pk;
        pk[0] = f2bf(st[j8][0]); pk[1] = f2bf(st[j8][1]);
        pk[2] = f2bf(st[j8][2]); pk[3] = f2bf(st[j8][3]);
        *(bf16x4*)&Plds[wave][c][j8 * 16 + q4 * 4] = pk;
      }
#pragma unroll
      for (int ks = 0; ks < 2; ++ks) {
        const bf16x8 pv = *(const bf16x8*)&Plds[wave][c][ks * 32 + q4 * 8];
#pragma unroll
        for (int dj = 0; dj < 8; ++dj) {
          const bf16x8 vv = *(const bf16x8*)
              &Vld[buf][((ks * 4 + q4) * 128 + dj * 16 + c) * 8];
          Ot[g][dj] = MFMA16(vv, pv, Ot[g][dj]);
        }
      }
    }
    __syncthreads();
  }

#pragma unroll
  for (int g = 0; g < 2; ++g) {
    const float inv = 1.0f / l_i[g];
    float* orow = out + ((size_t)b * Sq + q0 + g * 16 + c) * Eq + h * Dq;
#pragma unroll
    for (int dj = 0; dj < 8; ++dj) {
      float4 o;
      o.x = Ot[g][dj][0] * inv; o.y = Ot[g][dj][1] * inv;
      o.z = Ot[g][dj][2] * inv; o.w = Ot[g][dj][3] * inv;
      *(float4*)&orow[dj * 16 + q4 * 4] = o;
    }
  }
}

// ---------------------------------------------------------------------------
extern "C" void kernel_launch(void* const* d_in, const int* in_sizes, int n_in,
                              void* d_out, int out_size, void* d_ws,
                              size_t ws_size, hipStream_t stream) {
  const float* x = (const float*)d_in[0];
  // d_in[1] = mask (causal tril) — implemented analytically, not read.
  const float* w = (const float*)d_in[2];
  float* out = (float*)d_out;

  const size_t nX = (size_t)Bq * Sq * Eq;         // 8,388,608
  const size_t nW = (size_t)Eq * N3E;             // 12,582,912
  const size_t perT = (size_t)Bq * Hq * Sq * Dq;  // 8,388,608

  bf16* xb = (bf16*)d_ws;
  bf16* wt = xb + nX;
  bf16* qws = wt + nW;
  bf16* kws = qws + perT;
  bf16* vtws = kws + perT;
  float2* tbl = (float2*)(vtws + perT);  // 2048*64 float2 = 1 MB

  convert_x<<<nX / (256 * 8), 256, 0, stream>>>(x, xb);
  convert_wt<<<(Eq / 64) * (N3E / 64), 256, 0, stream>>>(w, wt);
  rope_table<<<(Sq * 64) / 256, 256, 0, stream>>>(tbl);

  gemm_qkv<<<768, 512, 0, stream>>>(xb, wt, tbl, qws, kws, vtws);

  dim3 g3(Sq / 128, Hq, Bq);  // 16 x 16 x 2, qt CU-paired
  attn_kernel<<<g3, 256, 0, stream>>>(qws, kws, vtws, out);
}

// Round 2
// 373.692 us; speedup vs baseline: 1.1784x; 1.0011x over previous
//
#include <hip/hip_runtime.h>

typedef __bf16 bf16;
typedef __bf16 bf16x8 __attribute__((ext_vector_type(8)));
typedef __bf16 bf16x4 __attribute__((ext_vector_type(4)));
typedef float f32x4 __attribute__((ext_vector_type(4)));

#define MFMA16(a, b, c) __builtin_amdgcn_mfma_f32_16x16x32_bf16(a, b, c, 0, 0, 0)

// Problem constants
#define Bq 2
#define Sq 2048
#define Eq 2048
#define Hq 16
#define Dq 128
#define N3E 6144

#define GLOAD_LDS16(gp, lp) \
  __builtin_amdgcn_global_load_lds( \
      (const __attribute__((address_space(1))) void*)(gp), \
      (__attribute__((address_space(3))) void*)(lp), 16, 0, 0)

__device__ __forceinline__ bf16 f2bf(float f) {
  unsigned u = __builtin_bit_cast(unsigned, f);
  u += 0x7FFFu + ((u >> 16) & 1u);
  unsigned short h = (unsigned short)(u >> 16);
  return __builtin_bit_cast(bf16, h);
}
__device__ __forceinline__ float bf2f(bf16 b) {
  unsigned short h = __builtin_bit_cast(unsigned short, b);
  return __builtin_bit_cast(float, (unsigned)h << 16);
}

// ---------------------------------------------------------------------------
// Kernel 0a: x fp32 -> xb bf16 (elementwise, 8 elems/thread)
// ---------------------------------------------------------------------------
__global__ __launch_bounds__(256) void convert_x(const float* __restrict__ x,
                                                 bf16* __restrict__ xb) {
  const size_t i = ((size_t)blockIdx.x * 256 + threadIdx.x) * 8;
  float4 a = *(const float4*)(x + i);
  float4 b = *(const float4*)(x + i + 4);
  bf16x8 o;
  o[0] = f2bf(a.x); o[1] = f2bf(a.y); o[2] = f2bf(a.z); o[3] = f2bf(a.w);
  o[4] = f2bf(b.x); o[5] = f2bf(b.y); o[6] = f2bf(b.z); o[7] = f2bf(b.w);
  *(bf16x8*)(xb + i) = o;
}

// ---------------------------------------------------------------------------
// Kernel 0b: W fp32 [k][n] -> wt bf16 [n][k] (64x64 LDS tile transpose)
// ---------------------------------------------------------------------------
__global__ __launch_bounds__(256) void convert_wt(const float* __restrict__ w,
                                                  bf16* __restrict__ wt) {
  __shared__ __align__(16) bf16 T[64][72];
  const int tid = threadIdx.x;
  const int kb = blockIdx.x & 31;  // 2048/64
  const int nb = blockIdx.x >> 5;  // 6144/64
  const int k0 = kb * 64, n0 = nb * 64;
  {
    const int kr = tid >> 4, nc = (tid & 15) * 4;
#pragma unroll
    for (int p = 0; p < 4; ++p) {
      const int k = kr + p * 16;
      float4 v = *(const float4*)(w + (size_t)(k0 + k) * N3E + n0 + nc);
      T[nc + 0][k] = f2bf(v.x);
      T[nc + 1][k] = f2bf(v.y);
      T[nc + 2][k] = f2bf(v.z);
      T[nc + 3][k] = f2bf(v.w);
    }
  }
  __syncthreads();
#pragma unroll
  for (int q = 0; q < 2; ++q) {
    const int id = q * 256 + tid;
    const int n = id >> 3, ch = id & 7;
    bf16x8 v = *(const bf16x8*)&T[n][ch * 8];
    *(bf16x8*)(wt + (size_t)(n0 + n) * Eq + k0 + ch * 8) = v;
  }
}

// ---------------------------------------------------------------------------
// Kernel 0c: RoPE cos/sin table [Sq][Dq/2] of float2 (1 MB).
// ---------------------------------------------------------------------------
__global__ __launch_bounds__(256) void rope_table(float2* __restrict__ tbl) {
  const int i = blockIdx.x * 256 + threadIdx.x;  // 0 .. Sq*64-1
  const int s = i >> 6, d = i & 63;
  const float freq = __expf(-(float)d * 0.14391157f);  // ln(10000)/64
  const float ang = (float)s * freq;
  float sv, cv;
  __sincosf(ang, &sv, &cv);
  tbl[i] = make_float2(cv, sv);
}

// ---------------------------------------------------------------------------
// Kernel 1: qkv = xb @ wt^T. 128(M)x256(N) tile, BK=64, ring-3 LDS (144 KiB),
// 512 threads = 8 waves (2M x 4N, 64x64/wave). Round-2 change: each K-tile is
// split into 4 PHASES (T3 fine interleave): {ds_read subtile || issue 2
// global_load_lds for tile t+2} -> barrier -> lgkmcnt(0) -> setprio(1) ->
// 8 MFMA -> setprio(0) -> barrier. Counted s_waitcnt vmcnt(6) ONCE per tile
// (end of phase 3) keeps t+2's 6 loads in flight across the barrier — never
// vmcnt(0) in the main loop (T4). Ring-3 makes this clobber-free by
// construction (writes go to slot (t+2)%3, reads from slot t%3).
// XOR column-swizzle applied on the GLOBAL source (rule 21) + same XOR on
// ds_read addresses: coalesced 128B global rows AND 2-way-max LDS banking.
// ---------------------------------------------------------------------------
__global__ __launch_bounds__(512, 2) void gemm_qkv(
    const bf16* __restrict__ xb, const bf16* __restrict__ wt,
    const float2* __restrict__ tbl, bf16* __restrict__ qws,
    bf16* __restrict__ kws, bf16* __restrict__ vtws) {
  // 3 slots x (A 128x64 + B 256x64) bf16 = 3 * 24576 elems = 144 KiB
  __shared__ __align__(16) bf16 LDS[3 * 24576];

  const int tid = threadIdx.x;
  const int lane = tid & 63, wv = tid >> 6;
  const int q4 = lane >> 4, c = lane & 15;
  const int wm = (wv >> 2) * 64;   // wave M offset: 0 / 64
  const int wn = (wv & 3) * 64;    // wave N offset: 0 / 64 / 128 / 192
  const int cx = c & 7;            // read-side XOR key

  // XCD swizzle: 768 blocks % 8 == 0 -> 96 consecutive wg per XCD.
  const int bid = blockIdx.x;
  const int wg = (bid & 7) * 96 + (bid >> 3);
  const int m0 = (wg / 24) * 128;
  const int n0 = (wg % 24) * 256;

  f32x4 acc[4][4];
#pragma unroll
  for (int i = 0; i < 4; ++i)
#pragma unroll
    for (int j = 0; j < 4; ++j) acc[i][j] = {0.f, 0.f, 0.f, 0.f};

  const int NT = Eq / 64;  // 32 K-tiles

  auto stageA = [&](int t, int st) {
    bf16* ab = LDS + st * 24576;
    const int k0 = t * 64;
#pragma unroll
    for (int it = 0; it < 2; ++it) {
      const int slot = it * 512 + tid;
      const int row = slot >> 3, kch = slot & 7;
      const int kcs = kch ^ (row & 7);  // source pre-swizzle (involution)
      GLOAD_LDS16(xb + (size_t)(m0 + row) * Eq + k0 + kcs * 8, ab + slot * 8);
    }
  };
  auto stageB = [&](int t, int st, int half) {
    bf16* bb = LDS + st * 24576 + 8192;
    const int k0 = t * 64;
#pragma unroll
    for (int it = 0; it < 2; ++it) {
      const int slot = (half * 2 + it) * 512 + tid;
      const int row = slot >> 3, kch = slot & 7;
      const int kcs = kch ^ (row & 7);
      GLOAD_LDS16(wt + (size_t)(n0 + row) * Eq + k0 + kcs * 8, bb + slot * 8);
    }
  };

  // Prologue: tiles 0,1 fully in flight; wait for tile 0 (6 newest = tile 1).
  stageA(0, 0); stageB(0, 0, 0); stageB(0, 0, 1);
  stageA(1, 1); stageB(1, 1, 0); stageB(1, 1, 1);
  asm volatile("s_waitcnt vmcnt(6)" ::: "memory");
  __builtin_amdgcn_s_barrier();

  int stC = 0;
#pragma unroll 1
  for (int t = 0; t < NT; ++t) {
    const bf16* A = LDS + stC * 24576;
    const bf16* Bb = A + 8192;
    int ss = stC + 2;
    if (ss >= 3) ss -= 3;
    const bool pf = (t + 2 < NT);
    bf16x8 af[4], b0, b1;

    // ---- phase 0: af(kk=0)x4 + b[0,1](kk=0); stage A(t+2); MFMA j=0,1 ----
#pragma unroll
    for (int i = 0; i < 4; ++i)
      af[i] = *(const bf16x8*)&A[(wm + i * 16 + c) * 64 + (q4 ^ cx) * 8];
    b0 = *(const bf16x8*)&Bb[(wn + 0 * 16 + c) * 64 + (q4 ^ cx) * 8];
    b1 = *(const bf16x8*)&Bb[(wn + 1 * 16 + c) * 64 + (q4 ^ cx) * 8];
    if (pf) stageA(t + 2, ss);
    __builtin_amdgcn_s_barrier();
    asm volatile("s_waitcnt lgkmcnt(0)" ::: "memory");
    __builtin_amdgcn_s_setprio(1);
#pragma unroll
    for (int i = 0; i < 4; ++i) {
      acc[i][0] = MFMA16(af[i], b0, acc[i][0]);
      acc[i][1] = MFMA16(af[i], b1, acc[i][1]);
    }
    __builtin_amdgcn_s_setprio(0);
    __builtin_amdgcn_s_barrier();

    // ---- phase 1: b[2,3](kk=0); stage B half0; MFMA j=2,3 ----
    b0 = *(const bf16x8*)&Bb[(wn + 2 * 16 + c) * 64 + (q4 ^ cx) * 8];
    b1 = *(const bf16x8*)&Bb[(wn + 3 * 16 + c) * 64 + (q4 ^ cx) * 8];
    if (pf) stageB(t + 2, ss, 0);
    __builtin_amdgcn_s_barrier();
    asm volatile("s_waitcnt lgkmcnt(0)" ::: "memory");
    __builtin_amdgcn_s_setprio(1);
#pragma unroll
    for (int i = 0; i < 4; ++i) {
      acc[i][2] = MFMA16(af[i], b0, acc[i][2]);
      acc[i][3] = MFMA16(af[i], b1, acc[i][3]);
    }
    __builtin_amdgcn_s_setprio(0);
    __builtin_amdgcn_s_barrier();

    // ---- phase 2: af(kk=32)x4 + b[0,1](kk=32); stage B half1; MFMA j=0,1 --
#pragma unroll
    for (int i = 0; i < 4; ++i)
      af[i] = *(const bf16x8*)&A[(wm + i * 16 + c) * 64 + ((4 + q4) ^ cx) * 8];
    b0 = *(const bf16x8*)&Bb[(wn + 0 * 16 + c) * 64 + ((4 + q4) ^ cx) * 8];
    b1 = *(const bf16x8*)&Bb[(wn + 1 * 16 + c) * 64 + ((4 + q4) ^ cx) * 8];
    if (pf) stageB(t + 2, ss, 1);
    __builtin_amdgcn_s_barrier();
    asm volatile("s_waitcnt lgkmcnt(0)" ::: "memory");
    __builtin_amdgcn_s_setprio(1);
#pragma unroll
    for (int i = 0; i < 4; ++i) {
      acc[i][0] = MFMA16(af[i], b0, acc[i][0]);
      acc[i][1] = MFMA16(af[i], b1, acc[i][1]);
    }
    __builtin_amdgcn_s_setprio(0);
    __builtin_amdgcn_s_barrier();

    // ---- phase 3: b[2,3](kk=32); MFMA j=2,3; counted end-of-tile wait ----
    b0 = *(const bf16x8*)&Bb[(wn + 2 * 16 + c) * 64 + ((4 + q4) ^ cx) * 8];
    b1 = *(const bf16x8*)&Bb[(wn + 3 * 16 + c) * 64 + ((4 + q4) ^ cx) * 8];
    __builtin_amdgcn_s_barrier();
    asm volatile("s_waitcnt lgkmcnt(0)" ::: "memory");
    __builtin_amdgcn_s_setprio(1);
#pragma unroll
    for (int i = 0; i < 4; ++i) {
      acc[i][2] = MFMA16(af[i], b0, acc[i][2]);
      acc[i][3] = MFMA16(af[i], b1, acc[i][3]);
    }
    __builtin_amdgcn_s_setprio(0);
    if (t + 1 < NT) {
      // Counted: drains tile t+1's loads (oldest), keeps t+2's 6 in flight.
      if (pf) asm volatile("s_waitcnt vmcnt(6)" ::: "memory");
      else    asm volatile("s_waitcnt vmcnt(0)" ::: "memory");
      __builtin_amdgcn_s_barrier();
    }
    stC = stC == 2 ? 0 : stC + 1;
  }
  __syncthreads();  // full drain once; LDS reused below

  // ---- epilogue: per-head (2 heads per 256-wide N tile) ----
  const int t3 = n0 >> 11;         // 0=q, 1=k, 2=v
  const int b = m0 >> 11;
  const int s0 = m0 & 2047;
  const int h0 = (n0 & 2047) >> 7;

  bf16* E = LDS;  // reused: [128][136] bf16 = 34816 B

  if (t3 == 2) {
#pragma unroll 1
    for (int hh = 0; hh < 2; ++hh) {
      if (((wv & 3) >> 1) == hh) {  // waves owning this head's 128 cols
#pragma unroll
        for (int i = 0; i < 4; ++i)
#pragma unroll
          for (int j = 0; j < 4; ++j) {
            bf16x4 pv;
            pv[0] = f2bf(acc[i][j][0]); pv[1] = f2bf(acc[i][j][1]);
            pv[2] = f2bf(acc[i][j][2]); pv[3] = f2bf(acc[i][j][3]);
            // transposed dump: E[d][s]
            *(bf16x4*)&E[((wn & 127) + j * 16 + c) * 136 + wm + i * 16 +
                         q4 * 4] = pv;
          }
      }
      __syncthreads();
      bf16* vbase = vtws + ((size_t)(b * Hq + h0 + hh) * Dq) * Sq + s0;
#pragma unroll
      for (int p = 0; p < 4; ++p) {
        const int id = p * 512 + tid;
        const int d = id >> 4, ch = id & 15;
        bf16x8 v = *(const bf16x8*)&E[d * 136 + ch * 8];
        *(bf16x8*)&vbase[(size_t)d * Sq + ch * 8] = v;
      }
      __syncthreads();
    }
  } else {
#pragma unroll 1
    for (int hh = 0; hh < 2; ++hh) {
      if (((wv & 3) >> 1) == hh) {
#pragma unroll
        for (int i = 0; i < 4; ++i)
#pragma unroll
          for (int j = 0; j < 4; ++j)
#pragma unroll
            for (int rr = 0; rr < 4; ++rr)
              E[(wm + i * 16 + q4 * 4 + rr) * 136 + (wn & 127) + j * 16 + c] =
                  f2bf(acc[i][j][rr]);
      }
      __syncthreads();
      bf16* hd = ((t3 == 0) ? qws : kws) +
                 ((size_t)(b * Hq + h0 + hh) * Sq + s0) * Dq;
#pragma unroll
      for (int p = 0; p < 2; ++p) {
        const int row = p * 64 + (tid >> 3);
        const int dlow = (tid & 7) * 8;
        const int s = s0 + row;
        bf16x8 lo = *(const bf16x8*)&E[row * 136 + dlow];
        bf16x8 hi = *(const bf16x8*)&E[row * 136 + 64 + dlow];
        const float2* tb = tbl + (size_t)s * 64 + dlow;
        bf16x8 olo, ohi;
#pragma unroll
        for (int e = 0; e < 8; ++e) {
          const float cv = tb[e].x, sv = tb[e].y;
          const float x1 = bf2f(lo[e]), x2 = bf2f(hi[e]);
          olo[e] = f2bf(x1 * cv - x2 * sv);
          ohi[e] = f2bf(x2 * cv + x1 * sv);
        }
        *(bf16x8*)&hd[(size_t)row * Dq + dlow] = olo;
        *(bf16x8*)&hd[(size_t)row * Dq + 64 + dlow] = ohi;
      }
      __syncthreads();
    }
  }
}

// ---------------------------------------------------------------------------
// Kernel 3: flash attention (R5 structure) + qt CU-pairing fix.
// Round-2 change: T5 s_setprio(1) around the QK^T and PV MFMA clusters
// (+4-7% measured on attn-structure kernels, m191).
// ---------------------------------------------------------------------------
__global__ __launch_bounds__(256, 2) void attn_kernel(
    const bf16* __restrict__ qws, const bf16* __restrict__ kws,
    const bf16* __restrict__ vtws, float* __restrict__ out) {
  __shared__ __align__(16) bf16 Kld[2][8192];
  __shared__ __align__(16) bf16 Vld[2][8192];
  __shared__ __align__(16) bf16 Plds[4][16][72];

  const int tid = threadIdx.x, lane = tid & 63, wave = tid >> 6;
  const int q4 = lane >> 4, c = lane & 15;
  const int h = blockIdx.y, b = blockIdx.z;
  const int qt = b ? blockIdx.x : (15 - blockIdx.x);  // CU-pair balance
  const size_t bh = (size_t)(b * Hq + h);
  const bf16* qbase = qws + bh * Sq * Dq;
  const bf16* kbase = kws + bh * Sq * Dq;
  const bf16* vbase = vtws + bh * Dq * Sq;
  const int q0 = qt * 128 + wave * 32;
  const float kSc = 0.08838834764831845f * 1.4426950408889634f;

  bf16x8 qf[2][4];
#pragma unroll
  for (int g = 0; g < 2; ++g)
#pragma unroll
    for (int ks = 0; ks < 4; ++ks)
      qf[g][ks] = *(const bf16x8*)
          &qbase[(size_t)(q0 + g * 16 + c) * Dq + ks * 32 + q4 * 8];

  f32x4 Ot[2][8];
  float m_i[2], l_i[2];
#pragma unroll
  for (int g = 0; g < 2; ++g) {
#pragma unroll
    for (int dj = 0; dj < 8; ++dj) Ot[g][dj] = {0.f, 0.f, 0.f, 0.f};
    m_i[g] = -1e30f; l_i[g] = 0.f;
  }

  const int nchunks = 2 * qt + 2;

#pragma unroll
  for (int it = 0; it < 4; ++it) {
    const int slot = it * 256 + tid;
    GLOAD_LDS16(kbase + (size_t)(slot & 63) * Dq + (slot >> 6) * 8,
                &Kld[0][slot * 8]);
    GLOAD_LDS16(vbase + (size_t)(slot & 127) * Sq + (slot >> 7) * 8,
                &Vld[0][slot * 8]);
  }
  __syncthreads();

  for (int kb = 0; kb < nchunks; ++kb) {
    const int buf = kb & 1;
    if (kb + 1 < nchunks) {
      const int nb = buf ^ 1;
      const int koff = (kb + 1) * 64;
#pragma unroll
      for (int it = 0; it < 4; ++it) {
        const int slot = it * 256 + tid;
        GLOAD_LDS16(kbase + (size_t)(koff + (slot & 63)) * Dq + (slot >> 6) * 8,
                    &Kld[nb][slot * 8]);
        GLOAD_LDS16(vbase + (size_t)(slot & 127) * Sq + koff + (slot >> 7) * 8,
                    &Vld[nb][slot * 8]);
      }
    }
    const bool masked = (kb >= 2 * qt);
#pragma unroll
    for (int g = 0; g < 2; ++g) {
      const int qg = q0 + g * 16 + c;
      f32x4 st[4];
#pragma unroll
      for (int j8 = 0; j8 < 4; ++j8) st[j8] = {0.f, 0.f, 0.f, 0.f};
      __builtin_amdgcn_s_setprio(1);
#pragma unroll
      for (int ks = 0; ks < 4; ++ks) {
        const bf16x8 qv = qf[g][ks];
#pragma unroll
        for (int j8 = 0; j8 < 4; ++j8) {
          const bf16x8 kv = *(const bf16x8*)
              &Kld[buf][((ks * 4 + q4) * 64 + j8 * 16 + c) * 8];
          st[j8] = MFMA16(kv, qv, st[j8]);
        }
      }
      __builtin_amdgcn_s_setprio(0);
      if (masked) {
        const int kb64 = kb * 64 + q4 * 4;
#pragma unroll
        for (int j8 = 0; j8 < 4; ++j8)
#pragma unroll
          for (int rr = 0; rr < 4; ++rr)
            if (kb64 + j8 * 16 + rr > qg) st[j8][rr] = -1e30f;
      }
      float mloc = -1e30f;
#pragma unroll
      for (int j8 = 0; j8 < 4; ++j8)
#pragma unroll
        for (int rr = 0; rr < 4; ++rr) mloc = fmaxf(mloc, st[j8][rr]);
      mloc = fmaxf(mloc, __shfl_xor(mloc, 16, 64));
      mloc = fmaxf(mloc, __shfl_xor(mloc, 32, 64));
      const float mn = fmaxf(m_i[g], mloc);
      const float alpha = exp2f((m_i[g] - mn) * kSc);
      m_i[g] = mn;
      float ssum = 0.f;
#pragma unroll
      for (int j8 = 0; j8 < 4; ++j8)
#pragma unroll
        for (int rr = 0; rr < 4; ++rr) {
          const float p = exp2f((st[j8][rr] - mn) * kSc);
          st[j8][rr] = p;
          ssum += p;
        }
      ssum += __shfl_xor(ssum, 16, 64);
      ssum += __shfl_xor(ssum, 32, 64);
      l_i[g] = l_i[g] * alpha + ssum;
#pragma unroll
      for (int dj = 0; dj < 8; ++dj) Ot[g][dj] *= alpha;
#pragma unroll
      for (int j8 = 0; j8 < 4; ++j8) {
        bf16x4 pk;
        pk[0] = f2bf(st[j8][0]); pk[1] = f2bf(st[j8][1]);
        pk[2] = f2bf(st[j8][2]); pk[3] = f2bf(st[j8][3]);
        *(bf16x4*)&Plds[wave][c][j8 * 16 + q4 * 4] = pk;
      }
      __builtin_amdgcn_s_setprio(1);
#pragma unroll
      for (int ks = 0; ks < 2; ++ks) {
        const bf16x8 pv = *(const bf16x8*)&Plds[wave][c][ks * 32 + q4 * 8];
#pragma unroll
        for (int dj = 0; dj < 8; ++dj) {
          const bf16x8 vv = *(const bf16x8*)
              &Vld[buf][((ks * 4 + q4) * 128 + dj * 16 + c) * 8];
          Ot[g][dj] = MFMA16(vv, pv, Ot[g][dj]);
        }
      }
      __builtin_amdgcn_s_setprio(0);
    }
    __syncthreads();
  }

#pragma unroll
  for (int g = 0; g < 2; ++g) {
    const float inv = 1.0f / l_i[g];
    float* orow = out + ((size_t)b * Sq + q0 + g * 16 + c) * Eq + h * Dq;
#pragma unroll
    for (int dj = 0; dj < 8; ++dj) {
      float4 o;
      o.x = Ot[g][dj][0] * inv; o.y = Ot[g][dj][1] * inv;
      o.z = Ot[g][dj][2] * inv; o.w = Ot[g][dj][3] * inv;
      *(float4*)&orow[dj * 16 + q4 * 4] = o;
    }
  }
}

// ---------------------------------------------------------------------------
extern "C" void kernel_launch(void* const* d_in, const int* in_sizes, int n_in,
                              void* d_out, int out_size, void* d_ws,
                              size_t ws_size, hipStream_t stream) {
  const float* x = (const float*)d_in[0];
  // d_in[1] = mask (causal tril) — implemented analytically, not read.
  const float* w = (const float*)d_in[2];
  float* out = (float*)d_out;

  const size_t nX = (size_t)Bq * Sq * Eq;         // 8,388,608
  const size_t nW = (size_t)Eq * N3E;             // 12,582,912
  const size_t perT = (size_t)Bq * Hq * Sq * Dq;  // 8,388,608

  bf16* xb = (bf16*)d_ws;
  bf16* wt = xb + nX;
  bf16* qws = wt + nW;
  bf16* kws = qws + perT;
  bf16* vtws = kws + perT;
  float2* tbl = (float2*)(vtws + perT);  // 2048*64 float2 = 1 MB

  convert_x<<<nX / (256 * 8), 256, 0, stream>>>(x, xb);
  convert_wt<<<(Eq / 64) * (N3E / 64), 256, 0, stream>>>(w, wt);
  rope_table<<<(Sq * 64) / 256, 256, 0, stream>>>(tbl);

  gemm_qkv<<<768, 512, 0, stream>>>(xb, wt, tbl, qws, kws, vtws);

  dim3 g3(Sq / 128, Hq, Bq);  // 16 x 16 x 2, qt CU-paired
  attn_kernel<<<g3, 256, 0, stream>>>(qws, kws, vtws, out);
}

// Round 3
// 371.579 us; speedup vs baseline: 1.1851x; 1.0057x over previous
//
#include <hip/hip_runtime.h>

typedef __bf16 bf16;
typedef __bf16 bf16x8 __attribute__((ext_vector_type(8)));
typedef __bf16 bf16x4 __attribute__((ext_vector_type(4)));
typedef float f32x4 __attribute__((ext_vector_type(4)));

#define MFMA16(a, b, c) __builtin_amdgcn_mfma_f32_16x16x32_bf16(a, b, c, 0, 0, 0)

// Problem constants
#define Bq 2
#define Sq 2048
#define Eq 2048
#define Hq 16
#define Dq 128
#define N3E 6144

#define GLOAD_LDS16(gp, lp) \
  __builtin_amdgcn_global_load_lds( \
      (const __attribute__((address_space(1))) void*)(gp), \
      (__attribute__((address_space(3))) void*)(lp), 16, 0, 0)

__device__ __forceinline__ bf16 f2bf(float f) {
  unsigned u = __builtin_bit_cast(unsigned, f);
  u += 0x7FFFu + ((u >> 16) & 1u);
  unsigned short h = (unsigned short)(u >> 16);
  return __builtin_bit_cast(bf16, h);
}
__device__ __forceinline__ float bf2f(bf16 b) {
  unsigned short h = __builtin_bit_cast(unsigned short, b);
  return __builtin_bit_cast(float, (unsigned)h << 16);
}

// ---------------------------------------------------------------------------
// Kernel 0a: x fp32 -> xb bf16 (elementwise, 8 elems/thread)
// ---------------------------------------------------------------------------
__global__ __launch_bounds__(256) void convert_x(const float* __restrict__ x,
                                                 bf16* __restrict__ xb) {
  const size_t i = ((size_t)blockIdx.x * 256 + threadIdx.x) * 8;
  float4 a = *(const float4*)(x + i);
  float4 b = *(const float4*)(x + i + 4);
  bf16x8 o;
  o[0] = f2bf(a.x); o[1] = f2bf(a.y); o[2] = f2bf(a.z); o[3] = f2bf(a.w);
  o[4] = f2bf(b.x); o[5] = f2bf(b.y); o[6] = f2bf(b.z); o[7] = f2bf(b.w);
  *(bf16x8*)(xb + i) = o;
}

// ---------------------------------------------------------------------------
// Kernel 0b: W fp32 [k][n] -> wt bf16 [n][k] (64x64 LDS tile transpose)
// ---------------------------------------------------------------------------
__global__ __launch_bounds__(256) void convert_wt(const float* __restrict__ w,
                                                  bf16* __restrict__ wt) {
  __shared__ __align__(16) bf16 T[64][72];
  const int tid = threadIdx.x;
  const int kb = blockIdx.x & 31;  // 2048/64
  const int nb = blockIdx.x >> 5;  // 6144/64
  const int k0 = kb * 64, n0 = nb * 64;
  {
    const int kr = tid >> 4, nc = (tid & 15) * 4;
#pragma unroll
    for (int p = 0; p < 4; ++p) {
      const int k = kr + p * 16;
      float4 v = *(const float4*)(w + (size_t)(k0 + k) * N3E + n0 + nc);
      T[nc + 0][k] = f2bf(v.x);
      T[nc + 1][k] = f2bf(v.y);
      T[nc + 2][k] = f2bf(v.z);
      T[nc + 3][k] = f2bf(v.w);
    }
  }
  __syncthreads();
#pragma unroll
  for (int q = 0; q < 2; ++q) {
    const int id = q * 256 + tid;
    const int n = id >> 3, ch = id & 7;
    bf16x8 v = *(const bf16x8*)&T[n][ch * 8];
    *(bf16x8*)(wt + (size_t)(n0 + n) * Eq + k0 + ch * 8) = v;
  }
}

// ---------------------------------------------------------------------------
// Kernel 0c: RoPE cos/sin table [Sq][Dq/2] of float2 (1 MB).
// ---------------------------------------------------------------------------
__global__ __launch_bounds__(256) void rope_table(float2* __restrict__ tbl) {
  const int i = blockIdx.x * 256 + threadIdx.x;  // 0 .. Sq*64-1
  const int s = i >> 6, d = i & 63;
  const float freq = __expf(-(float)d * 0.14391157f);  // ln(10000)/64
  const float ang = (float)s * freq;
  float sv, cv;
  __sincosf(ang, &sv, &cv);
  tbl[i] = make_float2(cv, sv);
}

// ---------------------------------------------------------------------------
// Kernel 1: qkv = xb @ wt^T. ROUND-1 STRUCTURE (verbatim revert): 128x256
// tile, BK=64, ring-3 LDS (144 KiB), 512 threads = 8 waves (2Mx4N,
// 64x64/wave), single barrier per K-tile with COUNTED s_waitcnt vmcnt(6).
// Round-2's 4-phase split (8 MFMA/barrier) regressed 124->139 us: phase
// splitting only pays at >=16 MFMA per barrier (m201 density) which needs a
// 128x64 per-wave tile. Reverted.
// ---------------------------------------------------------------------------
__global__ __launch_bounds__(512, 2) void gemm_qkv(
    const bf16* __restrict__ xb, const bf16* __restrict__ wt,
    const float2* __restrict__ tbl, bf16* __restrict__ qws,
    bf16* __restrict__ kws, bf16* __restrict__ vtws) {
  // 3 slots x (A 128x64 + B 256x64) bf16 = 3 * 24576 elems = 144 KiB
  __shared__ __align__(16) bf16 LDS[3 * 24576];

  const int tid = threadIdx.x;
  const int lane = tid & 63, wv = tid >> 6;
  const int q4 = lane >> 4, c = lane & 15;
  const int wm = (wv >> 2) * 64;   // wave M offset: 0 / 64
  const int wn = (wv & 3) * 64;    // wave N offset: 0 / 64 / 128 / 192
  const int cx = c & 7;            // read-side XOR key

  // XCD swizzle: 768 blocks % 8 == 0 -> 96 consecutive wg per XCD.
  const int bid = blockIdx.x;
  const int wg = (bid & 7) * 96 + (bid >> 3);
  const int m0 = (wg / 24) * 128;
  const int n0 = (wg % 24) * 256;

  f32x4 acc[4][4];
#pragma unroll
  for (int i = 0; i < 4; ++i)
#pragma unroll
    for (int j = 0; j < 4; ++j) acc[i][j] = {0.f, 0.f, 0.f, 0.f};

  const int NT = Eq / 64;  // 32 K-tiles

  auto stage = [&](int t, int st) {
    bf16* ab = LDS + st * 24576;
    bf16* bb = ab + 8192;
    const int k0 = t * 64;
    // A: 128 rows x 64 cols = 2 gloads; lanes 8-per-row -> 128B coalesced.
#pragma unroll
    for (int it = 0; it < 2; ++it) {
      const int slot = it * 512 + tid;
      const int row = slot >> 3, kch = slot & 7;
      const int kcs = kch ^ (row & 7);  // source pre-swizzle (involution)
      GLOAD_LDS16(xb + (size_t)(m0 + row) * Eq + k0 + kcs * 8, ab + slot * 8);
    }
    // B: 256 rows x 64 cols = 4 gloads.
#pragma unroll
    for (int it = 0; it < 4; ++it) {
      const int slot = it * 512 + tid;
      const int row = slot >> 3, kch = slot & 7;
      const int kcs = kch ^ (row & 7);
      GLOAD_LDS16(wt + (size_t)(n0 + row) * Eq + k0 + kcs * 8, bb + slot * 8);
    }
  };

  // Prologue: tiles 0,1 in flight; wait only for tile 0 (6 newest = tile 1).
  stage(0, 0);
  stage(1, 1);
  asm volatile("s_waitcnt vmcnt(6)" ::: "memory");
  __builtin_amdgcn_s_barrier();

  int stC = 0;
#pragma unroll 1
  for (int t = 0; t < NT; ++t) {
    if (t + 2 < NT) {
      int ss = stC + 2;
      if (ss >= 3) ss -= 3;
      stage(t + 2, ss);  // slot (t+2)%3: not read by tiles t, t+1
    }
    const bf16* A = LDS + stC * 24576;
    const bf16* Bb = A + 8192;
#pragma unroll
    for (int kk = 0; kk < 64; kk += 32) {
      const int bch = kk >> 3;  // 0 or 4
      bf16x8 af[4], bfr[4];
#pragma unroll
      for (int i = 0; i < 4; ++i)
        af[i] = *(const bf16x8*)
            &A[(wm + i * 16 + c) * 64 + ((bch + q4) ^ cx) * 8];
#pragma unroll
      for (int j = 0; j < 4; ++j)
        bfr[j] = *(const bf16x8*)
            &Bb[(wn + j * 16 + c) * 64 + ((bch + q4) ^ cx) * 8];
      __builtin_amdgcn_s_setprio(1);
#pragma unroll
      for (int i = 0; i < 4; ++i)
#pragma unroll
        for (int j = 0; j < 4; ++j)
          acc[i][j] = MFMA16(af[i], bfr[j], acc[i][j]);
      __builtin_amdgcn_s_setprio(0);
    }
    if (t + 1 < NT) {
      // Counted: drains tile t+1's loads (oldest), keeps t+2's 6 in flight.
      if (t + 2 < NT) asm volatile("s_waitcnt vmcnt(6)" ::: "memory");
      else            asm volatile("s_waitcnt vmcnt(0)" ::: "memory");
      __builtin_amdgcn_s_barrier();
    }
    stC = stC == 2 ? 0 : stC + 1;
  }
  __syncthreads();  // full drain once; LDS reused below

  // ---- epilogue: per-head (2 heads per 256-wide N tile) ----
  const int t3 = n0 >> 11;         // 0=q, 1=k, 2=v
  const int b = m0 >> 11;
  const int s0 = m0 & 2047;
  const int h0 = (n0 & 2047) >> 7;

  bf16* E = LDS;  // reused: [128][136] bf16 = 34816 B

  if (t3 == 2) {
#pragma unroll 1
    for (int hh = 0; hh < 2; ++hh) {
      if (((wv & 3) >> 1) == hh) {  // waves owning this head's 128 cols
#pragma unroll
        for (int i = 0; i < 4; ++i)
#pragma unroll
          for (int j = 0; j < 4; ++j) {
            bf16x4 pv;
            pv[0] = f2bf(acc[i][j][0]); pv[1] = f2bf(acc[i][j][1]);
            pv[2] = f2bf(acc[i][j][2]); pv[3] = f2bf(acc[i][j][3]);
            // transposed dump: E[d][s]
            *(bf16x4*)&E[((wn & 127) + j * 16 + c) * 136 + wm + i * 16 +
                         q4 * 4] = pv;
          }
      }
      __syncthreads();
      bf16* vbase = vtws + ((size_t)(b * Hq + h0 + hh) * Dq) * Sq + s0;
#pragma unroll
      for (int p = 0; p < 4; ++p) {
        const int id = p * 512 + tid;
        const int d = id >> 4, ch = id & 15;
        bf16x8 v = *(const bf16x8*)&E[d * 136 + ch * 8];
        *(bf16x8*)&vbase[(size_t)d * Sq + ch * 8] = v;
      }
      __syncthreads();
    }
  } else {
#pragma unroll 1
    for (int hh = 0; hh < 2; ++hh) {
      if (((wv & 3) >> 1) == hh) {
#pragma unroll
        for (int i = 0; i < 4; ++i)
#pragma unroll
          for (int j = 0; j < 4; ++j)
#pragma unroll
            for (int rr = 0; rr < 4; ++rr)
              E[(wm + i * 16 + q4 * 4 + rr) * 136 + (wn & 127) + j * 16 + c] =
                  f2bf(acc[i][j][rr]);
      }
      __syncthreads();
      bf16* hd = ((t3 == 0) ? qws : kws) +
                 ((size_t)(b * Hq + h0 + hh) * Sq + s0) * Dq;
#pragma unroll
      for (int p = 0; p < 2; ++p) {
        const int row = p * 64 + (tid >> 3);
        const int dlow = (tid & 7) * 8;
        const int s = s0 + row;
        bf16x8 lo = *(const bf16x8*)&E[row * 136 + dlow];
        bf16x8 hi = *(const bf16x8*)&E[row * 136 + 64 + dlow];
        const float2* tb = tbl + (size_t)s * 64 + dlow;
        bf16x8 olo, ohi;
#pragma unroll
        for (int e = 0; e < 8; ++e) {
          const float cv = tb[e].x, sv = tb[e].y;
          const float x1 = bf2f(lo[e]), x2 = bf2f(hi[e]);
          olo[e] = f2bf(x1 * cv - x2 * sv);
          ohi[e] = f2bf(x2 * cv + x1 * sv);
        }
        *(bf16x8*)&hd[(size_t)row * Dq + dlow] = olo;
        *(bf16x8*)&hd[(size_t)row * Dq + 64 + dlow] = ohi;
      }
      __syncthreads();
    }
  }
}

// ---------------------------------------------------------------------------
// Kernel 3: flash attention. Round-3 change: K- and V-fragment REGISTER
// SHARING across the two g-groups. Previously each g re-read its 16 K-frags
// and 16 V-frags from LDS (64 b128/chunk/wave); now ks-outer loops load each
// K/V fragment ONCE and feed both g's MFMAs (32 b128/chunk/wave). P is still
// staged through Plds per g, but read back into registers (pvr) immediately
// (same-wave in-order DS queue; compiler keeps order due to aliasing), so
// the PV loop can share each vv across both g. Softmax/mask math unchanged.
// ---------------------------------------------------------------------------
__global__ __launch_bounds__(256, 2) void attn_kernel(
    const bf16* __restrict__ qws, const bf16* __restrict__ kws,
    const bf16* __restrict__ vtws, float* __restrict__ out) {
  __shared__ __align__(16) bf16 Kld[2][8192];
  __shared__ __align__(16) bf16 Vld[2][8192];
  __shared__ __align__(16) bf16 Plds[4][16][72];

  const int tid = threadIdx.x, lane = tid & 63, wave = tid >> 6;
  const int q4 = lane >> 4, c = lane & 15;
  const int h = blockIdx.y, b = blockIdx.z;
  const int qt = b ? blockIdx.x : (15 - blockIdx.x);  // CU-pair balance
  const size_t bh = (size_t)(b * Hq + h);
  const bf16* qbase = qws + bh * Sq * Dq;
  const bf16* kbase = kws + bh * Sq * Dq;
  const bf16* vbase = vtws + bh * Dq * Sq;
  const int q0 = qt * 128 + wave * 32;
  const float kSc = 0.08838834764831845f * 1.4426950408889634f;

  bf16x8 qf[2][4];
#pragma unroll
  for (int g = 0; g < 2; ++g)
#pragma unroll
    for (int ks = 0; ks < 4; ++ks)
      qf[g][ks] = *(const bf16x8*)
          &qbase[(size_t)(q0 + g * 16 + c) * Dq + ks * 32 + q4 * 8];

  f32x4 Ot[2][8];
  float m_i[2], l_i[2];
#pragma unroll
  for (int g = 0; g < 2; ++g) {
#pragma unroll
    for (int dj = 0; dj < 8; ++dj) Ot[g][dj] = {0.f, 0.f, 0.f, 0.f};
    m_i[g] = -1e30f; l_i[g] = 0.f;
  }

  const int nchunks = 2 * qt + 2;

#pragma unroll
  for (int it = 0; it < 4; ++it) {
    const int slot = it * 256 + tid;
    GLOAD_LDS16(kbase + (size_t)(slot & 63) * Dq + (slot >> 6) * 8,
                &Kld[0][slot * 8]);
    GLOAD_LDS16(vbase + (size_t)(slot & 127) * Sq + (slot >> 7) * 8,
                &Vld[0][slot * 8]);
  }
  __syncthreads();

  for (int kb = 0; kb < nchunks; ++kb) {
    const int buf = kb & 1;
    if (kb + 1 < nchunks) {
      const int nb = buf ^ 1;
      const int koff = (kb + 1) * 64;
#pragma unroll
      for (int it = 0; it < 4; ++it) {
        const int slot = it * 256 + tid;
        GLOAD_LDS16(kbase + (size_t)(koff + (slot & 63)) * Dq + (slot >> 6) * 8,
                    &Kld[nb][slot * 8]);
        GLOAD_LDS16(vbase + (size_t)(slot & 127) * Sq + koff + (slot >> 7) * 8,
                    &Vld[nb][slot * 8]);
      }
    }
    const bool masked = (kb >= 2 * qt);

    // ---- QK^T, both g per K-fragment (K read once) ----
    f32x4 st[2][4];
#pragma unroll
    for (int g = 0; g < 2; ++g)
#pragma unroll
      for (int j8 = 0; j8 < 4; ++j8) st[g][j8] = {0.f, 0.f, 0.f, 0.f};
    __builtin_amdgcn_s_setprio(1);
#pragma unroll
    for (int ks = 0; ks < 4; ++ks) {
      bf16x8 kvv[4];
#pragma unroll
      for (int j8 = 0; j8 < 4; ++j8)
        kvv[j8] = *(const bf16x8*)
            &Kld[buf][((ks * 4 + q4) * 64 + j8 * 16 + c) * 8];
#pragma unroll
      for (int g = 0; g < 2; ++g)
#pragma unroll
        for (int j8 = 0; j8 < 4; ++j8)
          st[g][j8] = MFMA16(kvv[j8], qf[g][ks], st[g][j8]);
    }
    __builtin_amdgcn_s_setprio(0);

    // ---- softmax per g; P staged to LDS then read back into registers ----
    bf16x8 pvr[2][2];
#pragma unroll
    for (int g = 0; g < 2; ++g) {
      const int qg = q0 + g * 16 + c;
      if (masked) {
        const int kb64 = kb * 64 + q4 * 4;
#pragma unroll
        for (int j8 = 0; j8 < 4; ++j8)
#pragma unroll
          for (int rr = 0; rr < 4; ++rr)
            if (kb64 + j8 * 16 + rr > qg) st[g][j8][rr] = -1e30f;
      }
      float mloc = -1e30f;
#pragma unroll
      for (int j8 = 0; j8 < 4; ++j8)
#pragma unroll
        for (int rr = 0; rr < 4; ++rr) mloc = fmaxf(mloc, st[g][j8][rr]);
      mloc = fmaxf(mloc, __shfl_xor(mloc, 16, 64));
      mloc = fmaxf(mloc, __shfl_xor(mloc, 32, 64));
      const float mn = fmaxf(m_i[g], mloc);
      const float alpha = exp2f((m_i[g] - mn) * kSc);
      m_i[g] = mn;
      float ssum = 0.f;
#pragma unroll
      for (int j8 = 0; j8 < 4; ++j8)
#pragma unroll
        for (int rr = 0; rr < 4; ++rr) {
          const float p = exp2f((st[g][j8][rr] - mn) * kSc);
          st[g][j8][rr] = p;
          ssum += p;
        }
      ssum += __shfl_xor(ssum, 16, 64);
      ssum += __shfl_xor(ssum, 32, 64);
      l_i[g] = l_i[g] * alpha + ssum;
#pragma unroll
      for (int dj = 0; dj < 8; ++dj) Ot[g][dj] *= alpha;
#pragma unroll
      for (int j8 = 0; j8 < 4; ++j8) {
        bf16x4 pk;
        pk[0] = f2bf(st[g][j8][0]); pk[1] = f2bf(st[g][j8][1]);
        pk[2] = f2bf(st[g][j8][2]); pk[3] = f2bf(st[g][j8][3]);
        *(bf16x4*)&Plds[wave][c][j8 * 16 + q4 * 4] = pk;
      }
      // Read back into regs immediately (in-order DS queue; g=1's writes to
      // the same addresses cannot pass these reads).
      pvr[g][0] = *(const bf16x8*)&Plds[wave][c][0 * 32 + q4 * 8];
      pvr[g][1] = *(const bf16x8*)&Plds[wave][c][1 * 32 + q4 * 8];
    }

    // ---- PV, both g per V-fragment (V read once) ----
    __builtin_amdgcn_s_setprio(1);
#pragma unroll
    for (int ks = 0; ks < 2; ++ks) {
#pragma unroll
      for (int dj = 0; dj < 8; ++dj) {
        const bf16x8 vv = *(const bf16x8*)
            &Vld[buf][((ks * 4 + q4) * 128 + dj * 16 + c) * 8];
#pragma unroll
        for (int g = 0; g < 2; ++g)
          Ot[g][dj] = MFMA16(vv, pvr[g][ks], Ot[g][dj]);
      }
    }
    __builtin_amdgcn_s_setprio(0);
    __syncthreads();
  }

#pragma unroll
  for (int g = 0; g < 2; ++g) {
    const float inv = 1.0f / l_i[g];
    float* orow = out + ((size_t)b * Sq + q0 + g * 16 + c) * Eq + h * Dq;
#pragma unroll
    for (int dj = 0; dj < 8; ++dj) {
      float4 o;
      o.x = Ot[g][dj][0] * inv; o.y = Ot[g][dj][1] * inv;
      o.z = Ot[g][dj][2] * inv; o.w = Ot[g][dj][3] * inv;
      *(float4*)&orow[dj * 16 + q4 * 4] = o;
    }
  }
}

// ---------------------------------------------------------------------------
extern "C" void kernel_launch(void* const* d_in, const int* in_sizes, int n_in,
                              void* d_out, int out_size, void* d_ws,
                              size_t ws_size, hipStream_t stream) {
  const float* x = (const float*)d_in[0];
  // d_in[1] = mask (causal tril) — implemented analytically, not read.
  const float* w = (const float*)d_in[2];
  float* out = (float*)d_out;

  const size_t nX = (size_t)Bq * Sq * Eq;         // 8,388,608
  const size_t nW = (size_t)Eq * N3E;             // 12,582,912
  const size_t perT = (size_t)Bq * Hq * Sq * Dq;  // 8,388,608

  bf16* xb = (bf16*)d_ws;
  bf16* wt = xb + nX;
  bf16* qws = wt + nW;
  bf16* kws = qws + perT;
  bf16* vtws = kws + perT;
  float2* tbl = (float2*)(vtws + perT);  // 2048*64 float2 = 1 MB

  convert_x<<<nX / (256 * 8), 256, 0, stream>>>(x, xb);
  convert_wt<<<(Eq / 64) * (N3E / 64), 256, 0, stream>>>(w, wt);
  rope_table<<<(Sq * 64) / 256, 256, 0, stream>>>(tbl);

  gemm_qkv<<<768, 512, 0, stream>>>(xb, wt, tbl, qws, kws, vtws);

  dim3 g3(Sq / 128, Hq, Bq);  // 16 x 16 x 2, qt CU-paired
  attn_kernel<<<g3, 256, 0, stream>>>(qws, kws, vtws, out);
}